// Round 11
// baseline (249.092 us; speedup 1.0000x reference)
//
#include <hip/hip_runtime.h>

#define N_NODES 50000
#define N_REL 16
#define N_BASIS 8
#define D_IN 64
#define D_HID 64
#define N_CLASS 16
#define N_EDGES 800000
#define N_SBLK 196        // ceil(50000/256)
#define G1H_BLOCKS 391    // half of ceil(50000/64)=782
#define CNT_BLOCKS 3125   // ceil(800000/256)

typedef short s8v __attribute__((ext_vector_type(8)));    // 8 bf16 (4 VGPRs) MFMA A/B frag
typedef float f4v __attribute__((ext_vector_type(4)));    // 4 fp32 MFMA C/D frag

__device__ inline unsigned short f2bf(float f) {
    union { float f; unsigned u; } v; v.f = f;
    unsigned r = (v.u + 0x7FFFu + ((v.u >> 16) & 1u)) >> 16;   // RNE
    return (unsigned short)r;
}
__device__ inline float bf2f(unsigned short b) {
    union { unsigned u; float f; } v; v.u = ((unsigned)b) << 16;
    return v.f;
}
// accumulate 8 bf16 (packed in int4) scaled by inv into a[0..7]
__device__ __forceinline__ void acc8(float* a, float inv, int4 p) {
    a[0] += inv * __int_as_float((int)((unsigned)p.x << 16));
    a[1] += inv * __int_as_float(p.x & (int)0xFFFF0000u);
    a[2] += inv * __int_as_float((int)((unsigned)p.y << 16));
    a[3] += inv * __int_as_float(p.y & (int)0xFFFF0000u);
    a[4] += inv * __int_as_float((int)((unsigned)p.z << 16));
    a[5] += inv * __int_as_float(p.z & (int)0xFFFF0000u);
    a[6] += inv * __int_as_float((int)((unsigned)p.w << 16));
    a[7] += inv * __int_as_float(p.w & (int)0xFFFF0000u);
}

// ---------------- weights: w1T[r][o][k], w2T[r][o][k] in bf16; slot r=16 = self ----------------
__global__ __launch_bounds__(256) void k_wrel(const float* __restrict__ b1, const float* __restrict__ c1,
                                              const float* __restrict__ s1f,
                                              const float* __restrict__ b2, const float* __restrict__ c2,
                                              const float* __restrict__ s2f,
                                              unsigned short* __restrict__ w1T,
                                              unsigned short* __restrict__ w2T) {
    int idx = blockIdx.x * 256 + threadIdx.x;
    if (idx < 17 * 4096) {
        int r = idx >> 12, o = (idx >> 6) & 63, k = idx & 63;
        float acc = 0.f;
        if (r < 16) {
            #pragma unroll
            for (int b = 0; b < N_BASIS; b++) acc += c1[r * N_BASIS + b] * b1[b * 4096 + k * 64 + o];
        } else {
            acc = s1f[k * 64 + o];
        }
        w1T[idx] = f2bf(acc);
    } else {
        int idx2 = idx - 17 * 4096;
        if (idx2 < 17 * 1024) {
            int r = idx2 >> 10, o = (idx2 >> 6) & 15, k = idx2 & 63;
            float acc = 0.f;
            if (r < 16) {
                #pragma unroll
                for (int b = 0; b < N_BASIS; b++) acc += c2[r * N_BASIS + b] * b2[b * 1024 + k * 16 + o];
            } else {
                acc = s2f[k * 16 + o];
            }
            w2T[idx2] = f2bf(acc);
        }
    }
}

// ---------------- gemm1 tile body (R10-proven): LDS-dbuf weights + contiguous-store epilogue ----
__device__ __forceinline__ void gemm1_tile(int tile, int tid,
                                           const float* __restrict__ x,
                                           const unsigned short* __restrict__ w1T,
                                           unsigned short* __restrict__ t1,
                                           unsigned short* __restrict__ h,
                                           unsigned short* wbuf,    // 2*4096 shorts
                                           unsigned short* ou) {    // 4*1024 shorts
    int wv = tid >> 6, lane = tid & 63;
    int m = lane & 15, q = lane >> 4;
    int nb = tile * 64 + wv * 16;
    bool active = (nb < N_NODES);
    int n = active ? (nb + m) : 0;

    const float* xr = x + (size_t)n * 64 + q * 8;
    float4 x0a = *(const float4*)(xr);
    float4 x0b = *(const float4*)(xr + 4);
    float4 x1a = *(const float4*)(xr + 32);
    float4 x1b = *(const float4*)(xr + 36);
    s8v b0, b1;
    b0[0] = f2bf(x0a.x); b0[1] = f2bf(x0a.y); b0[2] = f2bf(x0a.z); b0[3] = f2bf(x0a.w);
    b0[4] = f2bf(x0b.x); b0[5] = f2bf(x0b.y); b0[6] = f2bf(x0b.z); b0[7] = f2bf(x0b.w);
    b1[0] = f2bf(x1a.x); b1[1] = f2bf(x1a.y); b1[2] = f2bf(x1a.z); b1[3] = f2bf(x1a.w);
    b1[4] = f2bf(x1b.x); b1[5] = f2bf(x1b.y); b1[6] = f2bf(x1b.z); b1[7] = f2bf(x1b.w);

    int c0 = tid, c1 = tid + 256;
    int p0s = (c0 >> 3) * 64 + (((c0 & 7) ^ ((c0 >> 3) & 7)) << 3);
    int p1s = (c1 >> 3) * 64 + (((c1 & 7) ^ ((c1 >> 3) & 7)) << 3);

    {
        const int4* src = (const int4*)w1T;
        int4 v0 = src[c0], v1 = src[c1];
        *(int4*)&wbuf[p0s] = v0;
        *(int4*)&wbuf[p1s] = v1;
    }
    __syncthreads();

    for (int w = 0; w < 17; w++) {
        int cur = w & 1;
        if (w < 16) {
            const int4* src = (const int4*)w1T + (w + 1) * 512;
            int4 v0 = src[c0], v1 = src[c1];
            *(int4*)&wbuf[(cur ^ 1) * 4096 + p0s] = v0;
            *(int4*)&wbuf[(cur ^ 1) * 4096 + p1s] = v1;
        }
        #pragma unroll
        for (int ct = 0; ct < 4; ct++) {
            int ro = ct * 16 + m;
            int pa = q ^ (ro & 7);
            int pb = (4 + q) ^ (ro & 7);
            s8v A0 = *(const s8v*)&wbuf[cur * 4096 + ro * 64 + pa * 8];
            s8v A1 = *(const s8v*)&wbuf[cur * 4096 + ro * 64 + pb * 8];
            f4v acc = (f4v){0.f, 0.f, 0.f, 0.f};
            acc = __builtin_amdgcn_mfma_f32_16x16x32_bf16(A0, b0, acc, 0, 0, 0);
            acc = __builtin_amdgcn_mfma_f32_16x16x32_bf16(A1, b1, acc, 0, 0, 0);
            ushort4 o4;
            o4.x = f2bf(acc[0]); o4.y = f2bf(acc[1]); o4.z = f2bf(acc[2]); o4.w = f2bf(acc[3]);
            int g = ct * 2 + (q >> 1);
            int pg = g ^ (m & 7);
            *(ushort4*)&ou[wv * 1024 + m * 64 + pg * 8 + (q & 1) * 4] = o4;
        }
        if (active) {
            int r1 = lane >> 3, g1 = lane & 7;
            int pg1 = g1 ^ (r1 & 7);
            int4 d0 = *(const int4*)&ou[wv * 1024 + r1 * 64 + pg1 * 8];
            int4 d1 = *(const int4*)&ou[wv * 1024 + (r1 + 8) * 64 + pg1 * 8];
            unsigned short* base = (w < 16) ? (t1 + ((size_t)w * N_NODES + nb) * 64)
                                            : (h + (size_t)nb * 64);
            *(int4*)(base + lane * 8) = d0;
            *(int4*)(base + 512 + lane * 8) = d1;
        }
        __syncthreads();
    }
}

// ---------------- FUSED A: gemm1 tiles [0,391) || counts histogram ----------------
__global__ __launch_bounds__(256) void k_fusedA(const float* __restrict__ x,
                                                const unsigned short* __restrict__ w1T,
                                                unsigned short* __restrict__ t1,
                                                unsigned short* __restrict__ h,
                                                const int* __restrict__ ei,
                                                const int* __restrict__ et,
                                                int* __restrict__ counts) {
    __shared__ __align__(16) unsigned short wbuf[2 * 4096];
    __shared__ __align__(16) unsigned short ou[4 * 1024];
    if (blockIdx.x >= G1H_BLOCKS) {
        int e = (blockIdx.x - G1H_BLOCKS) * 256 + threadIdx.x;
        if (e < N_EDGES) {
            int dst = ei[N_EDGES + e];
            int t = et[e];
            atomicAdd(&counts[dst * 16 + t], 1);
        }
        return;
    }
    gemm1_tile(blockIdx.x, threadIdx.x, x, w1T, t1, h, wbuf, ou);
}

// ---------------- FUSED B: gemm1 tiles [391,782) || scatter ----------------
__global__ __launch_bounds__(256) void k_fusedB(const float* __restrict__ x,
                                                const unsigned short* __restrict__ w1T,
                                                unsigned short* __restrict__ t1,
                                                unsigned short* __restrict__ h,
                                                const int* __restrict__ ei,
                                                const int* __restrict__ et,
                                                const int* __restrict__ counts,
                                                int* __restrict__ cursor,
                                                int2* __restrict__ sed) {
    __shared__ __align__(16) unsigned short wbuf[2 * 4096];
    __shared__ __align__(16) unsigned short ou[4 * 1024];
    if (blockIdx.x >= G1H_BLOCKS) {
        int e = (blockIdx.x - G1H_BLOCKS) * 256 + threadIdx.x;
        if (e < N_EDGES) {
            int src = ei[e];
            int dst = ei[N_EDGES + e];
            int t = et[e];
            int pos = atomicAdd(&cursor[dst], 1);
            float inv = 1.0f / (float)counts[dst * 16 + t];
            sed[pos] = make_int2((t << 16) | src, __float_as_int(inv));
        }
        return;
    }
    gemm1_tile(blockIdx.x + G1H_BLOCKS, threadIdx.x, x, w1T, t1, h, wbuf, ou);
}

// ---------------- scan stage 1: deg[n] = sum_t counts[n*16+t] ----------------
__global__ __launch_bounds__(256) void k_scan_local(const int* __restrict__ counts,
                                                    int* __restrict__ offsets,
                                                    int* __restrict__ bsum) {
    __shared__ int s[256];
    int t = threadIdx.x;
    int i = blockIdx.x * 256 + t;
    int v = 0;
    if (i < N_NODES) {
        const int4* c4 = (const int4*)(counts + i * 16);
        #pragma unroll
        for (int j = 0; j < 4; j++) {
            int4 cv = c4[j];
            v += cv.x + cv.y + cv.z + cv.w;
        }
    }
    s[t] = v;
    __syncthreads();
    #pragma unroll
    for (int off = 1; off < 256; off <<= 1) {
        int x = (t >= off) ? s[t - off] : 0;
        __syncthreads();
        s[t] += x;
        __syncthreads();
    }
    if (i < N_NODES) offsets[i] = s[t] - v;
    if (t == 255) bsum[blockIdx.x] = s[255];
}

__global__ __launch_bounds__(256) void k_scan_bsum(int* __restrict__ bsum) {
    __shared__ int s[256];
    int t = threadIdx.x;
    int v = (t < N_SBLK) ? bsum[t] : 0;
    s[t] = v;
    __syncthreads();
    #pragma unroll
    for (int off = 1; off < 256; off <<= 1) {
        int x = (t >= off) ? s[t - off] : 0;
        __syncthreads();
        s[t] += x;
        __syncthreads();
    }
    if (t < N_SBLK) bsum[t] = s[t] - v;
}

__global__ __launch_bounds__(256) void k_scan_final(int* __restrict__ offsets,
                                                    const int* __restrict__ bsum,
                                                    int* __restrict__ cursor) {
    int i = blockIdx.x * 256 + threadIdx.x;
    if (i < N_NODES) {
        int o = offsets[i] + bsum[blockIdx.x];
        offsets[i] = o;
        cursor[i] = o;
    }
    if (i == 0) offsets[N_NODES] = N_EDGES;
}

// ---------------- FUSED agg1 + relu + gemm2: wave = 16 nodes, accumulators ARE the B-frags ----
// lane: node m = lane&15, dims q*8..+7 and 32+q*8..+7 (q = lane>>4).
// Phase 1: per-edge gather (16 rows in flight per wave, x2 unroll), fp32 acc + self + relu.
// Phase 2: 17 MFMAs, A from w2T (L1/L2-hot, 34 KB), store t2 (bf16) + out self (fp32).
__global__ __launch_bounds__(256) void k_aggt1(const int* __restrict__ offsets,
                                               const int2* __restrict__ sed,
                                               const unsigned short* __restrict__ t1,
                                               const unsigned short* __restrict__ h,
                                               const unsigned short* __restrict__ w2T,
                                               unsigned short* __restrict__ t2,
                                               float* __restrict__ out) {
    int tid = threadIdx.x;
    int wv = tid >> 6, lane = tid & 63;
    int m = lane & 15, q = lane >> 4;
    int nb16 = blockIdx.x * 64 + wv * 16;
    if (nb16 >= N_NODES) return;          // wave-uniform, no barriers in kernel
    int n = nb16 + m;
    bool act = (n < N_NODES);
    int s = act ? offsets[n] : 0;
    int e = act ? offsets[n + 1] : 0;

    float a0[8], a1[8];
    #pragma unroll
    for (int j = 0; j < 8; j++) { a0[j] = 0.f; a1[j] = 0.f; }

    for (int i = s; i < e; i += 2) {
        int2 e0 = sed[i];
        bool has1 = (i + 1) < e;
        int2 e1 = has1 ? sed[i + 1] : e0;
        float inv0 = __int_as_float(e0.y);
        float inv1 = has1 ? __int_as_float(e1.y) : 0.f;
        const unsigned short* r0 =
            t1 + ((size_t)(((unsigned)e0.x >> 16) * N_NODES + (e0.x & 0xFFFF))) * 64;
        const unsigned short* r1 =
            t1 + ((size_t)(((unsigned)e1.x >> 16) * N_NODES + (e1.x & 0xFFFF))) * 64;
        int4 p00 = *(const int4*)(r0 + q * 8);
        int4 p01 = *(const int4*)(r0 + 32 + q * 8);
        int4 p10 = *(const int4*)(r1 + q * 8);
        int4 p11 = *(const int4*)(r1 + 32 + q * 8);
        acc8(a0, inv0, p00);
        acc8(a1, inv0, p01);
        acc8(a0, inv1, p10);
        acc8(a1, inv1, p11);
    }
    // self term from h (written by gemm1), then relu
    if (act) {
        int4 hs0 = *(const int4*)(h + (size_t)n * 64 + q * 8);
        int4 hs1 = *(const int4*)(h + (size_t)n * 64 + 32 + q * 8);
        acc8(a0, 1.0f, hs0);
        acc8(a1, 1.0f, hs1);
    }
    s8v b0, b1;
    #pragma unroll
    for (int j = 0; j < 8; j++) {
        float v0 = a0[j] > 0.f ? a0[j] : 0.f;
        float v1 = a1[j] > 0.f ? a1[j] : 0.f;
        b0[j] = (short)f2bf(v0);
        b1[j] = (short)f2bf(v1);
    }

    // phase 2: transform to t2 / out
    const unsigned short* wp = w2T + m * 64 + q * 8;
    for (int w = 0; w < 17; w++) {
        s8v A0 = *(const s8v*)(wp + (w << 10));
        s8v A1 = *(const s8v*)(wp + (w << 10) + 32);
        f4v acc = (f4v){0.f, 0.f, 0.f, 0.f};
        acc = __builtin_amdgcn_mfma_f32_16x16x32_bf16(A0, b0, acc, 0, 0, 0);
        acc = __builtin_amdgcn_mfma_f32_16x16x32_bf16(A1, b1, acc, 0, 0, 0);
        if (act) {
            if (w < 16) {
                ushort4 o;
                o.x = f2bf(acc[0]); o.y = f2bf(acc[1]); o.z = f2bf(acc[2]); o.w = f2bf(acc[3]);
                *(ushort4*)(t2 + ((size_t)w * N_NODES + n) * 16 + q * 4) = o;
            } else {
                *(float4*)(out + (size_t)n * 16 + q * 4) = make_float4(acc[0], acc[1], acc[2], acc[3]);
            }
        }
    }
}

// ---------------- layer-2 aggregation: wave = 16 nodes, register-direct, no reduce ----------------
// lane: node m = lane&15, dims q*4..+3.
__global__ __launch_bounds__(256) void k_agg2(const int* __restrict__ offsets,
                                              const int2* __restrict__ sed,
                                              const unsigned short* __restrict__ t2,
                                              float* __restrict__ out) {
    int tid = threadIdx.x;
    int wv = tid >> 6, lane = tid & 63;
    int m = lane & 15, q = lane >> 4;
    int nb16 = blockIdx.x * 64 + wv * 16;
    if (nb16 >= N_NODES) return;
    int n = nb16 + m;
    bool act = (n < N_NODES);
    int s = act ? offsets[n] : 0;
    int e = act ? offsets[n + 1] : 0;

    float a[4] = {0.f, 0.f, 0.f, 0.f};
    for (int i = s; i < e; i += 2) {
        int2 e0 = sed[i];
        bool has1 = (i + 1) < e;
        int2 e1 = has1 ? sed[i + 1] : e0;
        float inv0 = __int_as_float(e0.y);
        float inv1 = has1 ? __int_as_float(e1.y) : 0.f;
        const unsigned short* r0 =
            t2 + ((size_t)(((unsigned)e0.x >> 16) * N_NODES + (e0.x & 0xFFFF))) * 16 + q * 4;
        const unsigned short* r1 =
            t2 + ((size_t)(((unsigned)e1.x >> 16) * N_NODES + (e1.x & 0xFFFF))) * 16 + q * 4;
        ushort4 v0 = *(const ushort4*)(r0);
        ushort4 v1 = *(const ushort4*)(r1);
        a[0] += inv0 * bf2f(v0.x) + inv1 * bf2f(v1.x);
        a[1] += inv0 * bf2f(v0.y) + inv1 * bf2f(v1.y);
        a[2] += inv0 * bf2f(v0.z) + inv1 * bf2f(v1.z);
        a[3] += inv0 * bf2f(v0.w) + inv1 * bf2f(v1.w);
    }
    if (act) {
        float* p = out + (size_t)n * 16 + q * 4;
        float4 c = *(const float4*)p;
        c.x += a[0]; c.y += a[1]; c.z += a[2]; c.w += a[3];
        *(float4*)p = c;
    }
}

extern "C" void kernel_launch(void* const* d_in, const int* in_sizes, int n_in,
                              void* d_out, int out_size, void* d_ws, size_t ws_size,
                              hipStream_t stream) {
    const float* x      = (const float*)d_in[0];
    const float* bases1 = (const float*)d_in[1];
    const float* coeffs1= (const float*)d_in[2];
    const float* self1  = (const float*)d_in[3];
    const float* bases2 = (const float*)d_in[4];
    const float* coeffs2= (const float*)d_in[5];
    const float* self2  = (const float*)d_in[6];
    const int*   ei     = (const int*)d_in[7];
    const int*   et     = (const int*)d_in[8];
    float* out = (float*)d_out;

    char* ws = (char*)d_ws;
    int*            counts  = (int*)(ws + 0);                    //   3,200,000 (node-major [n*16+t])
    int*            offsets = (int*)(ws + 3200000);              //     200,064
    int*            cursor  = (int*)(ws + 3400064);              //     200,064
    unsigned short* w1T     = (unsigned short*)(ws + 3600128);   //     139,264
    unsigned short* w2T     = (unsigned short*)(ws + 3739392);   //      34,816
    int*            bsum    = (int*)(ws + 3774208);              //       1,024
    int2*           sed     = (int2*)(ws + 3775232);             //   6,400,000
    unsigned short* h       = (unsigned short*)(ws + 10175232);  //   6,400,000
    unsigned short* t1      = (unsigned short*)(ws + 16575232);  // 102,400,000 -> 118,975,232
    unsigned short* t2      = (unsigned short*)(ws + 118975232); //  25,600,000 -> 144,575,232
    // NOTE: t2 no longer aliases t1 — k_aggt1 reads t1 while writing t2.

    hipMemsetAsync(counts, 0, 3200000, stream);
    k_wrel<<<(17 * 4096 + 17 * 1024 + 255) / 256, 256, 0, stream>>>(
        bases1, coeffs1, self1, bases2, coeffs2, self2, w1T, w2T);
    k_fusedA<<<G1H_BLOCKS + CNT_BLOCKS, 256, 0, stream>>>(x, w1T, t1, h, ei, et, counts);
    k_scan_local<<<N_SBLK, 256, 0, stream>>>(counts, offsets, bsum);
    k_scan_bsum<<<1, 256, 0, stream>>>(bsum);
    k_scan_final<<<N_SBLK, 256, 0, stream>>>(offsets, bsum, cursor);
    k_fusedB<<<G1H_BLOCKS + CNT_BLOCKS, 256, 0, stream>>>(x, w1T, t1, h, ei, et, counts, cursor, sed);
    k_aggt1<<<782, 256, 0, stream>>>(offsets, sed, t1, h, w2T, t2, out);
    k_agg2<<<782, 256, 0, stream>>>(offsets, sed, t2, out);
}